// Round 5
// baseline (165.111 us; speedup 1.0000x reference)
//
#include <hip/hip_runtime.h>

typedef _Float16 f16;
typedef _Float16 f16x4 __attribute__((ext_vector_type(4)));
typedef _Float16 f16x8 __attribute__((ext_vector_type(8)));
typedef float f32x4 __attribute__((ext_vector_type(4)));

#define NB 8192
#define DIM 2048

// ---- workspace byte offsets (pack tables only; ~2.8 MB) ----
#define OFF_W1P    0u           // f32[256]
#define OFF_WOP    1024u        // f32[128]
#define OFF_W1HP   2048u        // f16 [16 mt][64 kc][64 lane][8] = 1 MB
#define OFF_W1LP   1050624u     // 1 MB
#define OFF_WOTHP  2099200u     // f16 [8][64][64][8] = 512 KB
#define OFF_W2HP   2623488u     // f16 [8][8][64][8] = 64 KB
#define OFF_W2LP   2689024u     // 64 KB
#define OFF_W2THP  2754560u     // f16 [16][4][64][8] = 64 KB

__device__ __forceinline__ f16 hi16(float x) { return (f16)x; }
__device__ __forceinline__ f16 lo16(float x, f16 h) { return (f16)(x - (float)h); }

// ---------------- merged prologue: packs + w1p + wop, one dispatch ----------------
// blocks 0..415: fragment packs (layouts identical to validated R2-R4)
// blocks 416..419: w1p column-slabs (no atomics, no memset needed)
// blocks 420..547: wop rows
__global__ void k_prep(const float* __restrict__ W1, const float* __restrict__ Wo,
                       const float* __restrict__ W2, const float* __restrict__ Wp,
                       f16* __restrict__ W1h, f16* __restrict__ W1l,
                       f16* __restrict__ WoTh, f16* __restrict__ W2h,
                       f16* __restrict__ W2l, f16* __restrict__ W2Th,
                       float* __restrict__ w1p, float* __restrict__ wop) {
  __shared__ float red[256];
  const int b = blockIdx.x, t = threadIdx.x;
  if (b < 416) {
    int tid = b * 256 + t;   // 106496 total
    int g, c, kc, nt;
    if (tid < 65536) {                 // W1: KC=64, NT=16
      int cid = tid; int lane = cid & 63; int kcnt = cid >> 6;
      kc = kcnt & 63; nt = kcnt >> 6; g = lane >> 4; c = lane & 15;
      f16x8 h8, l8;
      #pragma unroll
      for (int j = 0; j < 8; ++j) {
        float v = W1[(size_t)(kc * 32 + 8 * g + j) * 256 + nt * 16 + c];
        f16 h = hi16(v); h8[j] = h; l8[j] = lo16(v, h);
      }
      *(f16x8*)&W1h[(size_t)cid * 8] = h8;
      *(f16x8*)&W1l[(size_t)cid * 8] = l8;
    } else if (tid < 98304) {          // WoT: KC=64, NT=8
      int cid = tid - 65536; int lane = cid & 63; int kcnt = cid >> 6;
      kc = kcnt & 63; nt = kcnt >> 6; g = lane >> 4; c = lane & 15;
      f16x8 h8;
      #pragma unroll
      for (int j = 0; j < 8; ++j)
        h8[j] = hi16(Wo[(size_t)(nt * 16 + c) * 2048 + kc * 32 + 8 * g + j]);
      *(f16x8*)&WoTh[(size_t)cid * 8] = h8;
    } else if (tid < 102400) {         // W2: KC=8, NT=8
      int cid = tid - 98304; int lane = cid & 63; int kcnt = cid >> 6;
      kc = kcnt & 7; nt = kcnt >> 3; g = lane >> 4; c = lane & 15;
      f16x8 h8, l8;
      #pragma unroll
      for (int j = 0; j < 8; ++j) {
        float v = W2[(size_t)(kc * 32 + 8 * g + j) * 128 + nt * 16 + c];
        f16 h = hi16(v); h8[j] = h; l8[j] = lo16(v, h);
      }
      *(f16x8*)&W2h[(size_t)cid * 8] = h8;
      *(f16x8*)&W2l[(size_t)cid * 8] = l8;
    } else if (tid < 106496) {         // W2T: KC=4, NT=16
      int cid = tid - 102400; int lane = cid & 63; int kcnt = cid >> 6;
      kc = kcnt & 3; nt = kcnt >> 2; g = lane >> 4; c = lane & 15;
      f16x8 h8;
      #pragma unroll
      for (int j = 0; j < 8; ++j)
        h8[j] = hi16(W2[(size_t)(nt * 16 + c) * 128 + kc * 32 + 8 * g + j]);
      *(f16x8*)&W2Th[(size_t)cid * 8] = h8;
    }
  } else if (b < 420) {
    // w1p[i] = sum_d W1[d][i]*Wp[d]; slab of 64 cols, 4 row-chunks of 512
    int s = b - 416;
    int col = s * 64 + (t & 63);
    int chunk = t >> 6;
    float acc = 0.f;
    #pragma unroll 8
    for (int r = chunk * 512; r < chunk * 512 + 512; ++r)
      acc = fmaf(W1[(size_t)r * 256 + col], Wp[r], acc);
    red[t] = acc;            // t == chunk*64 + (t&63)
    __syncthreads();
    if (t < 64) w1p[s * 64 + t] = red[t] + red[64 + t] + red[128 + t] + red[192 + t];
  } else {
    // wop[j] = sum_d Wo[j][d]*Wp[d]
    int j = b - 420;
    float acc = 0.f;
    #pragma unroll
    for (int d = t; d < 2048; d += 256) acc = fmaf(Wo[(size_t)j * 2048 + d], Wp[d], acc);
    red[t] = acc; __syncthreads();
    for (int s2 = 128; s2 > 0; s2 >>= 1) { if (t < s2) red[t] += red[t + s2]; __syncthreads(); }
    if (t == 0) wop[j] = red[0];
  }
}

// ---- swizzled f16-offsets (16B-octet XOR swizzle) ----
__device__ __forceinline__ int sw256(int row, int o) { return (row * 32 + (o ^ (row & 15))) * 8; }
__device__ __forceinline__ int sw128(int row, int o) { return (row * 16 + (o ^ (row & 15))) * 8; }

#define MFMA16(a, b, acc) __builtin_amdgcn_mfma_f32_16x16x32_f16(a, b, acc, 0, 0, 0)

// ---------------- fully-fused network kernel ----------------
// 256 blocks x 512 thr (8 waves, 2/SIMD). Block = 32 sample-rows, K=2048.
// L1: double-buffered X LDS (1 barrier/sc) + depth-2 weight pipeline (4 sets).
// LDS exactly 64KB: XH0|XL0|XH1|XL1 (16KB each); post-L1 reuse:
//   XH0=H1h, XL0=H1l, XH1=DH, XL1=GA(8KB)+outr.
__global__ __launch_bounds__(512, 2) void k_fused(
    const float* __restrict__ X, const f16* __restrict__ W1h, const f16* __restrict__ W1l,
    const f16* __restrict__ WoTh, const f16* __restrict__ W2h, const f16* __restrict__ W2l,
    const f16* __restrict__ W2Th, const float* __restrict__ b1, const float* __restrict__ b2,
    const float* __restrict__ wop, const float* __restrict__ w1p, const float* __restrict__ bp,
    float* __restrict__ OUT) {
  __shared__ __align__(16) char smem[65536];
  f16* XH0 = (f16*)smem;                 // later H1h
  f16* XL0 = (f16*)(smem + 16384);       // later H1l
  f16* XH1 = (f16*)(smem + 32768);       // later DH
  f16* XL1 = (f16*)(smem + 49152);       // later GA
  f16* GA  = XL1;
  float* outr = (float*)(smem + 49152 + 16384 / 2);  // XL1 + 8KB

  const int tid = threadIdx.x;
  const int w = tid >> 6, lane = tid & 63;
  const int g = lane >> 4, c = lane & 15;
  const int m0 = blockIdx.x * 32;

  f32x4 accW[2][2], accG[2];
  #pragma unroll
  for (int m = 0; m < 2; ++m)
    #pragma unroll
    for (int nt = 0; nt < 2; ++nt) accW[m][nt] = (f32x4)0.f;
  #pragma unroll
  for (int nt = 0; nt < 2; ++nt) accG[nt] = (f32x4)0.f;

  // X prefetch: thread owns 16 consecutive k of one row per sc-chunk
  const int xrow = tid >> 4, xseg = tid & 15;
  const float4* xbase = (const float4*)(X + (size_t)(m0 + xrow) * DIM);
  float4 xr[4];
  #pragma unroll
  for (int i = 0; i < 4; ++i) xr[i] = xbase[xseg * 4 + i];

  // weight-fragment buffers: 4 sets -> depth-2 pipeline
  f16x8 whA[2], wlA[2], woA, whB[2], wlB[2], woB;
  f16x8 whC[2], wlC[2], woC, whD[2], wlD[2], woD;
#define LOADW(WH, WL, WO, KCG)                                              \
  {                                                                         \
    size_t kcg_ = (KCG);                                                    \
    _Pragma("unroll")                                                       \
    for (int m_ = 0; m_ < 2; ++m_) {                                        \
      size_t idx = (((size_t)(w * 2 + m_) * 64 + kcg_) * 64 + lane) * 8;    \
      WH[m_] = *(const f16x8*)&W1h[idx];                                    \
      WL[m_] = *(const f16x8*)&W1l[idx];                                    \
    }                                                                       \
    WO = *(const f16x8*)&WoTh[(((size_t)w * 64 + kcg_) * 64 + lane) * 8];   \
  }
#define L1MFMA(WH, WL, WO, KC8)                                             \
  {                                                                         \
    f16x8 bh[2], bl[2];                                                     \
    _Pragma("unroll")                                                       \
    for (int nt = 0; nt < 2; ++nt) {                                        \
      int a = sw256(nt * 16 + c, (KC8) * 4 + g);                            \
      bh[nt] = *(const f16x8*)&XHc[a];                                      \
      bl[nt] = *(const f16x8*)&XLc[a];                                      \
    }                                                                       \
    __builtin_amdgcn_s_setprio(1);                                          \
    _Pragma("unroll")                                                       \
    for (int m = 0; m < 2; ++m)                                             \
      _Pragma("unroll")                                                     \
      for (int nt = 0; nt < 2; ++nt) {                                      \
        accW[m][nt] = MFMA16(WH[m], bh[nt], accW[m][nt]);                   \
        accW[m][nt] = MFMA16(WH[m], bl[nt], accW[m][nt]);                   \
        accW[m][nt] = MFMA16(WL[m], bh[nt], accW[m][nt]);                   \
      }                                                                     \
    _Pragma("unroll")                                                       \
    for (int nt = 0; nt < 2; ++nt)                                          \
      accG[nt] = MFMA16(WO, bh[nt], accG[nt]);                              \
    __builtin_amdgcn_s_setprio(0);                                          \
  }

  // ======== Layer 1: pre1 = z@W1 (3-pass split), gh2 = z@WoT ========
  for (int sc = 0; sc < 8; ++sc) {
    f16* XHc = (sc & 1) ? XH1 : XH0;
    f16* XLc = XHc + 8192;
    // stage current chunk (regs already hold it); dbuf -> no pre-barrier
    #pragma unroll
    for (int i = 0; i < 2; ++i) {
      float q[8] = {xr[2*i].x, xr[2*i].y, xr[2*i].z, xr[2*i].w,
                    xr[2*i+1].x, xr[2*i+1].y, xr[2*i+1].z, xr[2*i+1].w};
      f16x8 h8, l8;
      #pragma unroll
      for (int j = 0; j < 8; ++j) { f16 h = hi16(q[j]); h8[j] = h; l8[j] = lo16(q[j], h); }
      int a = sw256(xrow, xseg * 2 + i);
      *(f16x8*)&XHc[a] = h8;
      *(f16x8*)&XLc[a] = l8;
    }
    __syncthreads();
    const size_t kb = (size_t)sc * 8;
    LOADW(whA, wlA, woA, kb + 0);
    LOADW(whB, wlB, woB, kb + 1);
    if (sc < 7) {                          // issue next X chunk early (HBM)
      #pragma unroll
      for (int i = 0; i < 4; ++i) xr[i] = xbase[(sc + 1) * 64 + xseg * 4 + i];
    }
    LOADW(whC, wlC, woC, kb + 2);
    L1MFMA(whA, wlA, woA, 0);
    LOADW(whD, wlD, woD, kb + 3);
    L1MFMA(whB, wlB, woB, 1);
    LOADW(whA, wlA, woA, kb + 4);
    L1MFMA(whC, wlC, woC, 2);
    LOADW(whB, wlB, woB, kb + 5);
    L1MFMA(whD, wlD, woD, 3);
    LOADW(whC, wlC, woC, kb + 6);
    L1MFMA(whA, wlA, woA, 4);
    LOADW(whD, wlD, woD, kb + 7);
    L1MFMA(whB, wlB, woB, 5);
    L1MFMA(whC, wlC, woC, 6);
    L1MFMA(whD, wlD, woD, 7);
  }
  __syncthreads();   // all L1 LDS reads done before buffer reuse

  // ======== h1 / dh1 / mask1 -> LDS (H1h=XH0, H1l=XL0, DH=XH1) ========
  if (tid < 32) outr[tid] = 0.f;
  unsigned mask1 = 0;
  #pragma unroll
  for (int m = 0; m < 2; ++m) {
    float4 b1f = *(const float4*)&b1[(w * 2 + m) * 16 + 4 * g];
    float b1a[4] = {b1f.x, b1f.y, b1f.z, b1f.w};
    #pragma unroll
    for (int nt = 0; nt < 2; ++nt) {
      f16x4 hh, hl, hd;
      #pragma unroll
      for (int rr = 0; rr < 4; ++rr) {
        float pre = accW[m][nt][rr];
        float a1 = pre + b1a[rr];
        bool mk = a1 > 0.f;
        float h1 = mk ? a1 : 0.f;
        f16 h = hi16(h1);
        hh[rr] = h; hl[rr] = lo16(h1, h);
        hd[rr] = mk ? hi16(pre) : (f16)0.f;
        mask1 |= (unsigned)mk << (m * 8 + nt * 4 + rr);
      }
      int row = nt * 16 + c;
      int o = w * 4 + m * 2 + (g >> 1);
      int a = sw256(row, o) + (g & 1) * 4;
      *(f16x4*)&XH0[a] = hh;   // H1h
      *(f16x4*)&XL0[a] = hl;   // H1l
      *(f16x4*)&XH1[a] = hd;   // DH
    }
  }
  __syncthreads();

  // ======== Layer 2: a2 = h1@W2 (3-pass) [+b2->mask2], da2 = dh1@W2h ========
  f32x4 acc2[2], accD[2];
  #pragma unroll
  for (int nt = 0; nt < 2; ++nt) { acc2[nt] = (f32x4)0.f; accD[nt] = (f32x4)0.f; }
  #pragma unroll
  for (int kc = 0; kc < 8; ++kc) {
    f16x8 w2hf, w2lf, bhh[2], bhl[2], bdh[2];
    {
      size_t idx = (((size_t)w * 8 + kc) * 64 + lane) * 8;
      w2hf = *(const f16x8*)&W2h[idx];
      w2lf = *(const f16x8*)&W2l[idx];
    }
    #pragma unroll
    for (int nt = 0; nt < 2; ++nt) {
      int a = sw256(nt * 16 + c, kc * 4 + g);
      bhh[nt] = *(const f16x8*)&XH0[a];
      bhl[nt] = *(const f16x8*)&XL0[a];
      bdh[nt] = *(const f16x8*)&XH1[a];
    }
    __builtin_amdgcn_s_setprio(1);
    #pragma unroll
    for (int nt = 0; nt < 2; ++nt) {
      acc2[nt] = MFMA16(w2hf, bhh[nt], acc2[nt]);
      acc2[nt] = MFMA16(w2hf, bhl[nt], acc2[nt]);
      acc2[nt] = MFMA16(w2lf, bhh[nt], acc2[nt]);
      accD[nt] = MFMA16(w2hf, bdh[nt], accD[nt]);
    }
    __builtin_amdgcn_s_setprio(0);
  }
  // epilogue: mask2, jx partial, ga2 -> LDS
  float jxv[2] = {0.f, 0.f};
  {
    float4 b2f = *(const float4*)&b2[w * 16 + 4 * g];
    float4 wpf = *(const float4*)&wop[w * 16 + 4 * g];
    float b2a[4] = {b2f.x, b2f.y, b2f.z, b2f.w};
    float wpa[4] = {wpf.x, wpf.y, wpf.z, wpf.w};
    #pragma unroll
    for (int nt = 0; nt < 2; ++nt) {
      f16x4 gav;
      #pragma unroll
      for (int rr = 0; rr < 4; ++rr) {
        float a2v = acc2[nt][rr] + b2a[rr];
        bool m2 = a2v > 0.f;
        gav[rr] = m2 ? hi16(accG[nt][rr]) : (f16)0.f;
        if (m2) jxv[nt] = fmaf(accD[nt][rr], wpa[rr], jxv[nt]);
      }
      int row = nt * 16 + c;
      int o = w * 2 + (g >> 1);
      int a = sw128(row, o) + (g & 1) * 4;
      *(f16x4*)&GA[a] = gav;
    }
  }
  __syncthreads();

  // ======== Layer 3: gh1 = ga2@W2T; jtx in-register ========
  f32x4 acc3[2][2];
  #pragma unroll
  for (int m = 0; m < 2; ++m)
    #pragma unroll
    for (int nt = 0; nt < 2; ++nt) acc3[m][nt] = (f32x4)0.f;
  #pragma unroll
  for (int kc = 0; kc < 4; ++kc) {
    f16x8 w2tf[2], bga[2];
    #pragma unroll
    for (int m = 0; m < 2; ++m) {
      size_t idx = (((size_t)(w * 2 + m) * 4 + kc) * 64 + lane) * 8;
      w2tf[m] = *(const f16x8*)&W2Th[idx];
    }
    #pragma unroll
    for (int nt = 0; nt < 2; ++nt) {
      int a = sw128(nt * 16 + c, kc * 4 + g);
      bga[nt] = *(const f16x8*)&GA[a];
    }
    __builtin_amdgcn_s_setprio(1);
    #pragma unroll
    for (int m = 0; m < 2; ++m)
      #pragma unroll
      for (int nt = 0; nt < 2; ++nt)
        acc3[m][nt] = MFMA16(w2tf[m], bga[nt], acc3[m][nt]);
    __builtin_amdgcn_s_setprio(0);
  }
  float jtv[2] = {0.f, 0.f};
  #pragma unroll
  for (int m = 0; m < 2; ++m) {
    float4 wpf = *(const float4*)&w1p[(w * 2 + m) * 16 + 4 * g];
    float wpa[4] = {wpf.x, wpf.y, wpf.z, wpf.w};
    #pragma unroll
    for (int nt = 0; nt < 2; ++nt)
      #pragma unroll
      for (int rr = 0; rr < 4; ++rr)
        if ((mask1 >> (m * 8 + nt * 4 + rr)) & 1)
          jtv[nt] = fmaf(acc3[m][nt][rr], wpa[rr], jtv[nt]);
  }
  float s0 = jxv[0] - jtv[0];
  float s1 = jxv[1] - jtv[1];
  s0 += __shfl_xor(s0, 16, 64); s0 += __shfl_xor(s0, 32, 64);
  s1 += __shfl_xor(s1, 16, 64); s1 += __shfl_xor(s1, 32, 64);
  if (lane < 16) {
    atomicAdd(&outr[lane], s0);
    atomicAdd(&outr[16 + lane], s1);
  }
  __syncthreads();
  if (tid < 32) OUT[m0 + tid] = outr[tid] + bp[0];
}

extern "C" void kernel_launch(void* const* d_in, const int* in_sizes, int n_in,
                              void* d_out, int out_size, void* d_ws, size_t ws_size,
                              hipStream_t stream) {
  (void)in_sizes; (void)n_in; (void)out_size; (void)ws_size;
  const float* x  = (const float*)d_in[0];
  const float* W1 = (const float*)d_in[1];
  const float* b1 = (const float*)d_in[2];
  const float* W2 = (const float*)d_in[3];
  const float* b2 = (const float*)d_in[4];
  const float* Wo = (const float*)d_in[5];
  // d_in[6] = bo: drops out of both jvp and vjp
  const float* Wp = (const float*)d_in[7];
  const float* bp = (const float*)d_in[8];
  char* ws = (char*)d_ws;
  float* OUT = (float*)d_out;

  float* w1p = (float*)(ws + OFF_W1P);
  float* wop = (float*)(ws + OFF_WOP);
  f16* W1hP  = (f16*)(ws + OFF_W1HP);
  f16* W1lP  = (f16*)(ws + OFF_W1LP);
  f16* WoThP = (f16*)(ws + OFF_WOTHP);
  f16* W2hP  = (f16*)(ws + OFF_W2HP);
  f16* W2lP  = (f16*)(ws + OFF_W2LP);
  f16* W2ThP = (f16*)(ws + OFF_W2THP);

  k_prep<<<548, 256, 0, stream>>>(W1, Wo, W2, Wp, W1hP, W1lP, WoThP,
                                  W2hP, W2lP, W2ThP, w1p, wop);
  k_fused<<<256, 512, 0, stream>>>(x, W1hP, W1lP, WoThP, W2hP, W2lP, W2ThP,
                                   b1, b2, wop, w1p, bp, OUT);
}

// Round 6
// 146.776 us; speedup vs baseline: 1.1249x; 1.1249x over previous
//
#include <hip/hip_runtime.h>

typedef _Float16 f16;
typedef _Float16 f16x4 __attribute__((ext_vector_type(4)));
typedef _Float16 f16x8 __attribute__((ext_vector_type(8)));
typedef float f32x4 __attribute__((ext_vector_type(4)));

#define NB 8192
#define DIM 2048

// ---- workspace byte offsets (pack tables only; ~2.8 MB) ----
#define OFF_W1P    0u           // f32[256]
#define OFF_WOP    1024u        // f32[128]
#define OFF_W1HP   2048u        // f16 [16 mt][64 kc][64 lane][8] = 1 MB
#define OFF_W1LP   1050624u     // 1 MB
#define OFF_WOTHP  2099200u     // f16 [8][64][64][8] = 512 KB
#define OFF_W2HP   2623488u     // f16 [8][8][64][8] = 64 KB
#define OFF_W2LP   2689024u     // 64 KB
#define OFF_W2THP  2754560u     // f16 [16][4][64][8] = 64 KB

__device__ __forceinline__ f16 hi16(float x) { return (f16)x; }
__device__ __forceinline__ f16 lo16(float x, f16 h) { return (f16)(x - (float)h); }

// ---------------- merged prologue: packs + w1p + wop, one dispatch ----------------
// blocks 0..415: fragment packs (layouts identical to validated R2-R5)
// blocks 416..431: w1p column-slabs (16 cols each, 16 row-chunks of 128)
// blocks 432..559: wop rows
__global__ void k_prep(const float* __restrict__ W1, const float* __restrict__ Wo,
                       const float* __restrict__ W2, const float* __restrict__ Wp,
                       f16* __restrict__ W1h, f16* __restrict__ W1l,
                       f16* __restrict__ WoTh, f16* __restrict__ W2h,
                       f16* __restrict__ W2l, f16* __restrict__ W2Th,
                       float* __restrict__ w1p, float* __restrict__ wop) {
  __shared__ float red[256];
  const int b = blockIdx.x, t = threadIdx.x;
  if (b < 416) {
    int tid = b * 256 + t;   // 106496 total
    int g, c, kc, nt;
    if (tid < 65536) {                 // W1: KC=64, NT=16
      int cid = tid; int lane = cid & 63; int kcnt = cid >> 6;
      kc = kcnt & 63; nt = kcnt >> 6; g = lane >> 4; c = lane & 15;
      f16x8 h8, l8;
      #pragma unroll
      for (int j = 0; j < 8; ++j) {
        float v = W1[(size_t)(kc * 32 + 8 * g + j) * 256 + nt * 16 + c];
        f16 h = hi16(v); h8[j] = h; l8[j] = lo16(v, h);
      }
      *(f16x8*)&W1h[(size_t)cid * 8] = h8;
      *(f16x8*)&W1l[(size_t)cid * 8] = l8;
    } else if (tid < 98304) {          // WoT: KC=64, NT=8
      int cid = tid - 65536; int lane = cid & 63; int kcnt = cid >> 6;
      kc = kcnt & 63; nt = kcnt >> 6; g = lane >> 4; c = lane & 15;
      f16x8 h8;
      #pragma unroll
      for (int j = 0; j < 8; ++j)
        h8[j] = hi16(Wo[(size_t)(nt * 16 + c) * 2048 + kc * 32 + 8 * g + j]);
      *(f16x8*)&WoTh[(size_t)cid * 8] = h8;
    } else if (tid < 102400) {         // W2: KC=8, NT=8
      int cid = tid - 98304; int lane = cid & 63; int kcnt = cid >> 6;
      kc = kcnt & 7; nt = kcnt >> 3; g = lane >> 4; c = lane & 15;
      f16x8 h8, l8;
      #pragma unroll
      for (int j = 0; j < 8; ++j) {
        float v = W2[(size_t)(kc * 32 + 8 * g + j) * 128 + nt * 16 + c];
        f16 h = hi16(v); h8[j] = h; l8[j] = lo16(v, h);
      }
      *(f16x8*)&W2h[(size_t)cid * 8] = h8;
      *(f16x8*)&W2l[(size_t)cid * 8] = l8;
    } else if (tid < 106496) {         // W2T: KC=4, NT=16
      int cid = tid - 102400; int lane = cid & 63; int kcnt = cid >> 6;
      kc = kcnt & 3; nt = kcnt >> 2; g = lane >> 4; c = lane & 15;
      f16x8 h8;
      #pragma unroll
      for (int j = 0; j < 8; ++j)
        h8[j] = hi16(W2[(size_t)(nt * 16 + c) * 128 + kc * 32 + 8 * g + j]);
      *(f16x8*)&W2Th[(size_t)cid * 8] = h8;
    }
  } else if (b < 432) {
    // w1p[i] = sum_d W1[d][i]*Wp[d]; 16 blocks x 16 cols; 16 chunks of 128 rows
    int s = b - 416;
    int cc = t & 15, chunk = t >> 4;
    int col = s * 16 + cc;
    float acc = 0.f;
    #pragma unroll 8
    for (int r = chunk * 128; r < chunk * 128 + 128; ++r)
      acc = fmaf(W1[(size_t)r * 256 + col], Wp[r], acc);
    red[t] = acc;
    __syncthreads();
    if (t < 16) {
      float sum = 0.f;
      #pragma unroll
      for (int ch = 0; ch < 16; ++ch) sum += red[ch * 16 + t];
      w1p[s * 16 + t] = sum;
    }
  } else {
    // wop[j] = sum_d Wo[j][d]*Wp[d]
    int j = b - 432;
    float acc = 0.f;
    #pragma unroll
    for (int d = t; d < 2048; d += 256) acc = fmaf(Wo[(size_t)j * 2048 + d], Wp[d], acc);
    red[t] = acc; __syncthreads();
    for (int s2 = 128; s2 > 0; s2 >>= 1) { if (t < s2) red[t] += red[t + s2]; __syncthreads(); }
    if (t == 0) wop[j] = red[0];
  }
}

// ---- swizzled f16-offsets (16B-octet XOR swizzle) ----
__device__ __forceinline__ int sw256(int row, int o) { return (row * 32 + (o ^ (row & 15))) * 8; }
__device__ __forceinline__ int sw128(int row, int o) { return (row * 16 + (o ^ (row & 15))) * 8; }

#define MFMA16(a, b, acc) __builtin_amdgcn_mfma_f32_16x16x32_f16(a, b, acc, 0, 0, 0)

// ---------------- fully-fused network kernel ----------------
// 256 blocks x 1024 thr (16 waves, 4 waves/SIMD). Block = 32 sample-rows, K=2048.
// Wave w owns feature mtile w everywhere: W1/W2T 16 mtiles -> 1/wave;
// WoT/W2 8 mtiles -> waves 0-7. Same LDS layout + fragment maps as R5 (validated).
__global__ __launch_bounds__(1024, 4) void k_fused(
    const float* __restrict__ X, const f16* __restrict__ W1h, const f16* __restrict__ W1l,
    const f16* __restrict__ WoTh, const f16* __restrict__ W2h, const f16* __restrict__ W2l,
    const f16* __restrict__ W2Th, const float* __restrict__ b1, const float* __restrict__ b2,
    const float* __restrict__ wop, const float* __restrict__ w1p, const float* __restrict__ bp,
    float* __restrict__ OUT) {
  __shared__ __align__(16) char smem[65536];
  f16* XH0 = (f16*)smem;                 // later H1h
  f16* XL0 = (f16*)(smem + 16384);       // later H1l
  f16* XH1 = (f16*)(smem + 32768);       // later DH
  f16* XL1 = (f16*)(smem + 49152);       // later GA (8KB)
  f16* GA  = XL1;
  float* outr = (float*)(smem + 57344);

  const int tid = threadIdx.x;
  const int w = tid >> 6, lane = tid & 63;
  const int g = lane >> 4, c = lane & 15;
  const int m0 = blockIdx.x * 32;

  f32x4 accW[2], accG[2];
  #pragma unroll
  for (int nt = 0; nt < 2; ++nt) { accW[nt] = (f32x4)0.f; accG[nt] = (f32x4)0.f; }

  // X staging: thread owns one 8-float octet of one row per sc-chunk
  const int xrow = tid >> 5, xseg = tid & 31;
  const float4* xbase = (const float4*)(X + (size_t)(m0 + xrow) * DIM);
  float4 xr[2];
  xr[0] = xbase[xseg * 2];
  xr[1] = xbase[xseg * 2 + 1];

  // weight-fragment double buffers
  f16x8 whA, wlA, woA, whB, wlB, woB;
#define LOADW(WH, WL, WO, KCG)                                              \
  {                                                                         \
    size_t idx = (((size_t)w * 64 + (KCG)) * 64 + lane) * 8;                \
    WH = *(const f16x8*)&W1h[idx];                                          \
    WL = *(const f16x8*)&W1l[idx];                                          \
    if (w < 8) WO = *(const f16x8*)&WoTh[idx];                              \
  }
#define L1MFMA(WH, WL, WO, KC8)                                             \
  {                                                                         \
    f16x8 bh[2], bl[2];                                                     \
    _Pragma("unroll")                                                       \
    for (int nt = 0; nt < 2; ++nt) {                                        \
      int a = sw256(nt * 16 + c, (KC8) * 4 + g);                            \
      bh[nt] = *(const f16x8*)&XHc[a];                                      \
      bl[nt] = *(const f16x8*)&XLc[a];                                      \
    }                                                                       \
    __builtin_amdgcn_s_setprio(1);                                          \
    _Pragma("unroll")                                                       \
    for (int nt = 0; nt < 2; ++nt) {                                        \
      accW[nt] = MFMA16(WH, bh[nt], accW[nt]);                              \
      accW[nt] = MFMA16(WH, bl[nt], accW[nt]);                              \
      accW[nt] = MFMA16(WL, bh[nt], accW[nt]);                              \
    }                                                                       \
    if (w < 8) {                                                            \
      _Pragma("unroll")                                                     \
      for (int nt = 0; nt < 2; ++nt)                                        \
        accG[nt] = MFMA16(WO, bh[nt], accG[nt]);                            \
    }                                                                       \
    __builtin_amdgcn_s_setprio(0);                                          \
  }

  // ======== Layer 1: pre1 = z@W1 (3-pass split), gh2 = z@WoT ========
  for (int sc = 0; sc < 8; ++sc) {
    f16* XHc = (sc & 1) ? XH1 : XH0;
    f16* XLc = XHc + 8192;
    {
      float q[8] = {xr[0].x, xr[0].y, xr[0].z, xr[0].w,
                    xr[1].x, xr[1].y, xr[1].z, xr[1].w};
      f16x8 h8, l8;
      #pragma unroll
      for (int j = 0; j < 8; ++j) { f16 h = hi16(q[j]); h8[j] = h; l8[j] = lo16(q[j], h); }
      int a = sw256(xrow, xseg);
      *(f16x8*)&XHc[a] = h8;
      *(f16x8*)&XLc[a] = l8;
    }
    __syncthreads();
    const size_t kb = (size_t)sc * 8;
    LOADW(whA, wlA, woA, kb + 0);
    LOADW(whB, wlB, woB, kb + 1);
    if (sc < 7) {                          // issue next X chunk early (HBM)
      xr[0] = xbase[(sc + 1) * 64 + xseg * 2];
      xr[1] = xbase[(sc + 1) * 64 + xseg * 2 + 1];
    }
    L1MFMA(whA, wlA, woA, 0);  LOADW(whA, wlA, woA, kb + 2);
    L1MFMA(whB, wlB, woB, 1);  LOADW(whB, wlB, woB, kb + 3);
    L1MFMA(whA, wlA, woA, 2);  LOADW(whA, wlA, woA, kb + 4);
    L1MFMA(whB, wlB, woB, 3);  LOADW(whB, wlB, woB, kb + 5);
    L1MFMA(whA, wlA, woA, 4);  LOADW(whA, wlA, woA, kb + 6);
    L1MFMA(whB, wlB, woB, 5);  LOADW(whB, wlB, woB, kb + 7);
    L1MFMA(whA, wlA, woA, 6);
    L1MFMA(whB, wlB, woB, 7);
  }
  __syncthreads();   // all L1 LDS reads done before buffer reuse

  // ======== h1 / dh1 / mask1 -> LDS (H1h=XH0, H1l=XL0, DH=XH1) ========
  if (tid < 32) outr[tid] = 0.f;
  unsigned mask1 = 0;
  {
    float4 b1f = *(const float4*)&b1[w * 16 + 4 * g];
    float b1a[4] = {b1f.x, b1f.y, b1f.z, b1f.w};
    #pragma unroll
    for (int nt = 0; nt < 2; ++nt) {
      f16x4 hh, hl, hd;
      #pragma unroll
      for (int rr = 0; rr < 4; ++rr) {
        float pre = accW[nt][rr];
        float a1 = pre + b1a[rr];
        bool mk = a1 > 0.f;
        float h1 = mk ? a1 : 0.f;
        f16 h = hi16(h1);
        hh[rr] = h; hl[rr] = lo16(h1, h);
        hd[rr] = mk ? hi16(pre) : (f16)0.f;
        mask1 |= (unsigned)mk << (nt * 4 + rr);
      }
      int row = nt * 16 + c;
      int o = w * 2 + (g >> 1);
      int a = sw256(row, o) + (g & 1) * 4;
      *(f16x4*)&XH0[a] = hh;   // H1h
      *(f16x4*)&XL0[a] = hl;   // H1l
      *(f16x4*)&XH1[a] = hd;   // DH
    }
  }
  __syncthreads();

  // ======== Layer 2 (waves 0-7): a2 = h1@W2 (3-pass) [+b2->mask2], da2 = dh1@W2h ========
  float jxv[2] = {0.f, 0.f};
  if (w < 8) {
    f32x4 acc2[2], accD[2];
    #pragma unroll
    for (int nt = 0; nt < 2; ++nt) { acc2[nt] = (f32x4)0.f; accD[nt] = (f32x4)0.f; }
    #pragma unroll
    for (int kc = 0; kc < 8; ++kc) {
      f16x8 w2hf, w2lf, bhh[2], bhl[2], bdh[2];
      {
        size_t idx = (((size_t)w * 8 + kc) * 64 + lane) * 8;
        w2hf = *(const f16x8*)&W2h[idx];
        w2lf = *(const f16x8*)&W2l[idx];
      }
      #pragma unroll
      for (int nt = 0; nt < 2; ++nt) {
        int a = sw256(nt * 16 + c, kc * 4 + g);
        bhh[nt] = *(const f16x8*)&XH0[a];
        bhl[nt] = *(const f16x8*)&XL0[a];
        bdh[nt] = *(const f16x8*)&XH1[a];
      }
      __builtin_amdgcn_s_setprio(1);
      #pragma unroll
      for (int nt = 0; nt < 2; ++nt) {
        acc2[nt] = MFMA16(w2hf, bhh[nt], acc2[nt]);
        acc2[nt] = MFMA16(w2hf, bhl[nt], acc2[nt]);
        acc2[nt] = MFMA16(w2lf, bhh[nt], acc2[nt]);
        accD[nt] = MFMA16(w2hf, bdh[nt], accD[nt]);
      }
      __builtin_amdgcn_s_setprio(0);
    }
    // epilogue: mask2, jx partial, ga2 -> LDS
    float4 b2f = *(const float4*)&b2[w * 16 + 4 * g];
    float4 wpf = *(const float4*)&wop[w * 16 + 4 * g];
    float b2a[4] = {b2f.x, b2f.y, b2f.z, b2f.w};
    float wpa[4] = {wpf.x, wpf.y, wpf.z, wpf.w};
    #pragma unroll
    for (int nt = 0; nt < 2; ++nt) {
      f16x4 gav;
      #pragma unroll
      for (int rr = 0; rr < 4; ++rr) {
        float a2v = acc2[nt][rr] + b2a[rr];
        bool m2 = a2v > 0.f;
        gav[rr] = m2 ? hi16(accG[nt][rr]) : (f16)0.f;
        if (m2) jxv[nt] = fmaf(accD[nt][rr], wpa[rr], jxv[nt]);
      }
      int row = nt * 16 + c;
      int o = w * 2 + (g >> 1);
      int a = sw128(row, o) + (g & 1) * 4;
      *(f16x4*)&GA[a] = gav;
    }
  }
  __syncthreads();

  // ======== Layer 3: gh1 = ga2@W2T; jtx in-register ========
  f32x4 acc3[2];
  #pragma unroll
  for (int nt = 0; nt < 2; ++nt) acc3[nt] = (f32x4)0.f;
  #pragma unroll
  for (int kc = 0; kc < 4; ++kc) {
    f16x8 w2tf, bga[2];
    w2tf = *(const f16x8*)&W2Th[(((size_t)w * 4 + kc) * 64 + lane) * 8];
    #pragma unroll
    for (int nt = 0; nt < 2; ++nt) {
      int a = sw128(nt * 16 + c, kc * 4 + g);
      bga[nt] = *(const f16x8*)&GA[a];
    }
    __builtin_amdgcn_s_setprio(1);
    #pragma unroll
    for (int nt = 0; nt < 2; ++nt)
      acc3[nt] = MFMA16(w2tf, bga[nt], acc3[nt]);
    __builtin_amdgcn_s_setprio(0);
  }
  float jtv[2] = {0.f, 0.f};
  {
    float4 wpf = *(const float4*)&w1p[w * 16 + 4 * g];
    float wpa[4] = {wpf.x, wpf.y, wpf.z, wpf.w};
    #pragma unroll
    for (int nt = 0; nt < 2; ++nt)
      #pragma unroll
      for (int rr = 0; rr < 4; ++rr)
        if ((mask1 >> (nt * 4 + rr)) & 1)
          jtv[nt] = fmaf(acc3[nt][rr], wpa[rr], jtv[nt]);
  }
  float s0 = jxv[0] - jtv[0];
  float s1 = jxv[1] - jtv[1];
  s0 += __shfl_xor(s0, 16, 64); s0 += __shfl_xor(s0, 32, 64);
  s1 += __shfl_xor(s1, 16, 64); s1 += __shfl_xor(s1, 32, 64);
  if (lane < 16) {
    atomicAdd(&outr[lane], s0);
    atomicAdd(&outr[16 + lane], s1);
  }
  __syncthreads();
  if (tid < 32) OUT[m0 + tid] = outr[tid] + bp[0];
}

extern "C" void kernel_launch(void* const* d_in, const int* in_sizes, int n_in,
                              void* d_out, int out_size, void* d_ws, size_t ws_size,
                              hipStream_t stream) {
  (void)in_sizes; (void)n_in; (void)out_size; (void)ws_size;
  const float* x  = (const float*)d_in[0];
  const float* W1 = (const float*)d_in[1];
  const float* b1 = (const float*)d_in[2];
  const float* W2 = (const float*)d_in[3];
  const float* b2 = (const float*)d_in[4];
  const float* Wo = (const float*)d_in[5];
  // d_in[6] = bo: drops out of both jvp and vjp
  const float* Wp = (const float*)d_in[7];
  const float* bp = (const float*)d_in[8];
  char* ws = (char*)d_ws;
  float* OUT = (float*)d_out;

  float* w1p = (float*)(ws + OFF_W1P);
  float* wop = (float*)(ws + OFF_WOP);
  f16* W1hP  = (f16*)(ws + OFF_W1HP);
  f16* W1lP  = (f16*)(ws + OFF_W1LP);
  f16* WoThP = (f16*)(ws + OFF_WOTHP);
  f16* W2hP  = (f16*)(ws + OFF_W2HP);
  f16* W2lP  = (f16*)(ws + OFF_W2LP);
  f16* W2ThP = (f16*)(ws + OFF_W2THP);

  k_prep<<<560, 256, 0, stream>>>(W1, Wo, W2, Wp, W1hP, W1lP, WoThP,
                                  W2hP, W2lP, W2ThP, w1p, wop);
  k_fused<<<256, 1024, 0, stream>>>(x, W1hP, W1lP, WoThP, W2hP, W2lP, W2ThP,
                                    b1, b2, wop, w1p, bp, OUT);
}